// Round 6
// baseline (113.499 us; speedup 1.0000x reference)
//
#include <hip/hip_runtime.h>

// SpatialEngram: out[b,o,i,j] = (table @ proj_w.T + proj_b)[idx[b,i,j]][o]
// where idx = trunc(mean_c(abs(3x3_sum(trunc(x*100)))%P))
//
// Round 6: split fused kernel into two single-personality streaming kernels.
//   K1 proj_table: tp[P][64] = table @ proj_w.T + proj_b  (ws, 2.56 MB)
//   K2 idx_kernel: integer path -> packed u16 idx[b][y][x]  (ws, 2 MB)
//                  (pure read stream: 134 MB of x)
//   K3 expand_kernel: coalesced idx load -> tp gather (L1/L2-hot, idx
//                  concentrates near ~240) -> register transpose ->
//                  nontemporal float4 stores (pure 268 MB write stream,
//                  fill-kernel-like, ~7 TB/s achievable)

#define CH  32
#define HH  512
#define WW  512
#define EE  64
#define OUT 64
#define PP  10000

#define TWPX 256              // idx kernel: tile width in pixels (64 thr x 4 px)
#define HW   (HH * WW)        // 262144 = 2^18

typedef float f32x4 __attribute__((ext_vector_type(4)));

__global__ __launch_bounds__(256) void proj_table_kernel(
    const float* __restrict__ table, const float* __restrict__ pw,
    const float* __restrict__ pb, float* __restrict__ tp) {
  __shared__ float sW[EE * OUT];          // sW[e*64 + o] = pw[o*64 + e]
  const int t = threadIdx.x;              // 0..255
  for (int i = t; i < EE * OUT; i += 256) {
    int o = i >> 6, e = i & 63;
    sW[e * OUT + o] = pw[i];
  }
  __syncthreads();
  const int p = blockIdx.x * 4 + (t >> 6);
  const int o = t & 63;
  const float4* trow = (const float4*)(table + (size_t)p * EE);
  float s0 = pb[o], s1 = 0.f, s2 = 0.f, s3 = 0.f;
  #pragma unroll
  for (int e4 = 0; e4 < EE / 4; ++e4) {
    float4 tv = trow[e4];                 // wave-uniform per 64-lane group
    s0 = fmaf(tv.x, sW[(4 * e4 + 0) * OUT + o], s0);
    s1 = fmaf(tv.y, sW[(4 * e4 + 1) * OUT + o], s1);
    s2 = fmaf(tv.z, sW[(4 * e4 + 2) * OUT + o], s2);
    s3 = fmaf(tv.w, sW[(4 * e4 + 3) * OUT + o], s3);
  }
  tp[(size_t)p * OUT + o] = (s0 + s1) + (s2 + s3);
}

__device__ __forceinline__ int q3(float a, float b, float c) {
  // column sum of trunc(v*100) over 3 rows; (int) truncates toward zero
  return (int)(a * 100.0f) + (int)(b * 100.0f) + (int)(c * 100.0f);
}

__global__ __launch_bounds__(256) void idx_kernel(
    const float* __restrict__ x, unsigned int* __restrict__ idx16) {
  const int tx  = threadIdx.x;            // 0..63
  const int ty  = threadIdx.y;            // 0..3
  const int gx0 = blockIdx.x * TWPX;
  const int y   = blockIdx.y * 4 + ty;
  const int b   = blockIdx.z;
  const int x0  = gx0 + tx * 4;

  const int ym1 = max(y - 1, 0);
  const int yp1 = min(y + 1, HH - 1);
  const size_t rm1 = (size_t)ym1 * WW + x0;
  const size_t r0  = (size_t)y   * WW + x0;
  const size_t rp1 = (size_t)yp1 * WW + x0;

  const bool edge = (tx == 0) || (tx == 63);
  const int  ecol = (tx == 0) ? max(gx0 - 1, 0) : min(gx0 + TWPX, WW - 1);
  const size_t em1 = (size_t)ym1 * WW + ecol;
  const size_t e0  = (size_t)y   * WW + ecol;
  const size_t ep1 = (size_t)yp1 * WW + ecol;

  const float* xb = x + (size_t)b * CH * HW;

  int acc0 = 0, acc1 = 0, acc2 = 0, acc3 = 0;
  #pragma unroll 2
  for (int c = 0; c < CH; ++c) {
    const float* xc = xb + (size_t)c * HW;
    float4 a = *(const float4*)(xc + rm1);
    float4 m = *(const float4*)(xc + r0);
    float4 p = *(const float4*)(xc + rp1);

    int cs0 = q3(a.x, m.x, p.x);
    int cs1 = q3(a.y, m.y, p.y);
    int cs2 = q3(a.z, m.z, p.z);
    int cs3 = q3(a.w, m.w, p.w);

    int csl = __shfl(cs3, tx - 1, 64);    // junk for tx==0 (overwritten)
    int csr = __shfl(cs0, tx + 1, 64);    // junk for tx==63 (overwritten)
    if (edge) {
      int e = q3(xc[em1], xc[e0], xc[ep1]);
      if (tx == 0) csl = e; else csr = e;
    }

    int h0 = csl + cs0 + cs1;
    int h1 = cs0 + cs1 + cs2;
    int h2 = cs1 + cs2 + cs3;
    int h3 = cs2 + cs3 + csr;

    acc0 += (int)((unsigned)(h0 < 0 ? -h0 : h0) % PP);
    acc1 += (int)((unsigned)(h1 < 0 ? -h1 : h1) % PP);
    acc2 += (int)((unsigned)(h2 < 0 ? -h2 : h2) % PP);
    acc3 += (int)((unsigned)(h3 < 0 ? -h3 : h3) % PP);
  }
  // mean over 32 channels, exact in f32; trunc of nonneg == >>5
  const unsigned i0 = (unsigned)(acc0 >> 5), i1 = (unsigned)(acc1 >> 5);
  const unsigned i2 = (unsigned)(acc2 >> 5), i3 = (unsigned)(acc3 >> 5);

  // pack 4 u16 into 8B; pixel index multiple of 4 -> uint2-aligned
  const size_t pix = (size_t)b * HW + (size_t)y * WW + x0;
  uint2 pk = make_uint2(i0 | (i1 << 16), i2 | (i3 << 16));
  *(uint2*)((unsigned short*)idx16 + pix) = pk;
}

__device__ __forceinline__ void nt_store4(float* p, float a, float b, float c, float d) {
  f32x4 v = {a, b, c, d};
  __builtin_nontemporal_store(v, (f32x4*)p);
}

__global__ __launch_bounds__(256) void expand_kernel(
    const unsigned short* __restrict__ idx16, const float* __restrict__ tp,
    float* __restrict__ out) {
  const unsigned tid  = blockIdx.x * 256 + threadIdx.x;
  const unsigned pix0 = tid * 4;                 // 4 consecutive x-pixels
  const unsigned b    = pix0 >> 18;              // HW = 2^18
  const unsigned rem  = pix0 & (HW - 1);

  const uint2 pk = ((const uint2*)idx16)[tid];
  const unsigned i0 = pk.x & 0xFFFFu, i1 = pk.x >> 16;
  const unsigned i2 = pk.y & 0xFFFFu, i3 = pk.y >> 16;

  const float4* t0 = (const float4*)(tp + (size_t)i0 * OUT);
  const float4* t1 = (const float4*)(tp + (size_t)i1 * OUT);
  const float4* t2 = (const float4*)(tp + (size_t)i2 * OUT);
  const float4* t3 = (const float4*)(tp + (size_t)i3 * OUT);

  float* ob = out + (size_t)b * OUT * HW + rem;
  #pragma unroll 4
  for (int k = 0; k < OUT / 4; ++k) {
    float4 va = t0[k], vb = t1[k], vc = t2[k], vd = t3[k];
    float* o0 = ob + (size_t)(4 * k) * HW;
    nt_store4(o0,          va.x, vb.x, vc.x, vd.x);
    nt_store4(o0 + HW,     va.y, vb.y, vc.y, vd.y);
    nt_store4(o0 + 2 * HW, va.z, vb.z, vc.z, vd.z);
    nt_store4(o0 + 3 * HW, va.w, vb.w, vc.w, vd.w);
  }
}

extern "C" void kernel_launch(void* const* d_in, const int* in_sizes, int n_in,
                              void* d_out, int out_size, void* d_ws, size_t ws_size,
                              hipStream_t stream) {
  const float* x     = (const float*)d_in[0];  // (4,32,512,512)
  const float* table = (const float*)d_in[1];  // (10000,64)
  const float* pw    = (const float*)d_in[2];  // (64,64)
  const float* pb    = (const float*)d_in[3];  // (64,)
  float* out = (float*)d_out;                  // (4,64,512,512)

  const int B = in_sizes[0] / (CH * HW);       // 4

  float* tp = (float*)d_ws;                              // 2.56 MB
  unsigned int* idx16 = (unsigned int*)((char*)d_ws + (size_t)PP * OUT * 4);  // 2 MB

  proj_table_kernel<<<PP / 4, 256, 0, stream>>>(table, pw, pb, tp);

  dim3 block(64, 4, 1);
  dim3 grid(WW / TWPX, HH / 4, B);             // (2, 128, 4)
  idx_kernel<<<grid, block, 0, stream>>>(x, idx16);

  const unsigned total_px = (unsigned)B * HW;  // 1M
  expand_kernel<<<total_px / 4 / 256, 256, 0, stream>>>(
      (const unsigned short*)idx16, tp, out);
}